// Round 15
// baseline (118.372 us; speedup 1.0000x reference)
//
#include <hip/hip_runtime.h>
#include <stdint.h>

#define B_  2
#define S_  2048
#define D_  1024
#define H_  16
#define DK_ 64

using bf16x8 = __attribute__((ext_vector_type(8))) short;
using f32x4  = __attribute__((ext_vector_type(4))) float;

__device__ __forceinline__ unsigned short f2bf(float f) {
    union { float f; uint32_t u; } v; v.f = f;
    uint32_t r = v.u + 0x7FFFu + ((v.u >> 16) & 1u);
    return (unsigned short)(r >> 16);
}

// pack two f32 -> one u32 of two bf16 (low = s0), RNE in HW
__device__ __forceinline__ uint32_t cvtpk(float lo, float hi) {
    uint32_t r;
    asm("v_cvt_pk_bf16_f32 %0, %1, %2" : "=v"(r) : "v"(lo), "v"(hi));
    return r;
}
// a' = {a(0-31), b(0-31)} ; b' = {a(32-63), b(32-63)}
__device__ __forceinline__ void ps32(uint32_t& a, uint32_t& b) {
    asm volatile("v_permlane32_swap_b32 %0, %1" : "+v"(a), "+v"(b));
}
// 16-lane rows: odd rows of a <-> even rows of b
__device__ __forceinline__ void ps16(uint32_t& a, uint32_t& b) {
    asm volatile("v_permlane16_swap_b32 %0, %1" : "+v"(a), "+v"(b));
}

// async global->LDS, 16B per lane; LDS dest is wave-uniform base + lane*16
#define GLD16(G, L) __builtin_amdgcn_global_load_lds( \
    (const __attribute__((address_space(1))) void*)(const void*)(G), \
    (__attribute__((address_space(3))) void*)(void*)(L), 16, 0, 0)

// ---------------- unified prep: x->bf16 and 4 weights->bf16 ----------------
// grid 8192: [0,4096) x-convert, [4096,8192) weights
__global__ __launch_bounds__(256) void k_prep(
    const float* __restrict__ x,
    const float* __restrict__ Wq, const float* __restrict__ Wk,
    const float* __restrict__ Wv, const float* __restrict__ Wo,
    unsigned short* __restrict__ xb,
    unsigned short* __restrict__ wqb, unsigned short* __restrict__ wkb,
    unsigned short* __restrict__ wvb, unsigned short* __restrict__ wob)
{
    const int bid = blockIdx.x, tid = threadIdx.x;
    const float* s;
    unsigned short* d;
    int i;
    if (bid < 4096) {
        s = x; d = xb; i = bid * 256 + tid;
    } else {
        const int w = (bid - 4096) >> 10;
        s = w == 0 ? Wq : w == 1 ? Wk : w == 2 ? Wv : Wo;
        d = w == 0 ? wqb : w == 1 ? wkb : w == 2 ? wvb : wob;
        i = ((bid - 4096) & 1023) * 256 + tid;
    }
    float4 v = ((const float4*)s)[i];
    union { unsigned short u[4]; uint2 dd; } o;
    o.u[0] = f2bf(v.x); o.u[1] = f2bf(v.y); o.u[2] = f2bf(v.z); o.u[3] = f2bf(v.w);
    ((uint2*)d)[i] = o.dd;
}

// ---------------- GEMM: C[m][n] = sum_k A[m][k] * W[n][k]  (B^T input) ------
// conflict-free XOR swizzle (both-sides) + 2-phase prefetch (round-8 proven).
// TM = tile M (128 or 64). TM=64 doubles blocks for the output projection.
template<int MODE, int TM>
__global__ __launch_bounds__(256) void k_gemm_bt(
    const unsigned short* __restrict__ A,
    const unsigned short* __restrict__ W0,
    const unsigned short* __restrict__ W1,
    const unsigned short* __restrict__ W2,
    void* __restrict__ C0, void* __restrict__ C1, void* __restrict__ C2,
    int M, int N, int K)
{
    constexpr int MI  = TM / 32;       // m-frags per wave (128->4, 64->2)
    constexpr int ACH = TM / 64;       // A chunks staged per wave
    __shared__ __align__(16) unsigned short As[2][TM * 32];
    __shared__ __align__(16) unsigned short Bs[2][128 * 32];

    const int tid  = threadIdx.x;
    const int wid  = tid >> 6, lane = tid & 63;
    const int m16  = lane & 15, g = lane >> 4;
    const int m0   = blockIdx.x * TM, n0 = blockIdx.y * 128;
    const unsigned short* Wm = blockIdx.z == 0 ? W0 : (blockIdx.z == 1 ? W1 : W2);
    void* Cm = blockIdx.z == 0 ? C0 : (blockIdx.z == 1 ? C1 : C2);

    const int wm = (wid >> 1) * (TM / 2), wn = (wid & 1) * 64;
    const int srow = lane >> 2;
    const int scol = ((lane & 3) ^ ((lane >> 3) & 3)) * 8;
    const int sw8  = (m16 >> 1) & 3;

    const f32x4 fz = {0.f, 0.f, 0.f, 0.f};
    f32x4 acc[MI][4];
#pragma unroll
    for (int i = 0; i < MI; ++i)
#pragma unroll
        for (int j = 0; j < 4; ++j) acc[i][j] = fz;

#pragma unroll
    for (int c = 0; c < ACH; ++c) {
        const int chunk = wid * ACH + c;
        GLD16(A + (size_t)(m0 + chunk * 16 + srow) * K + scol, &As[0][chunk * 512]);
    }
#pragma unroll
    for (int c = 0; c < 2; ++c) {
        const int chunk = wid * 2 + c;
        GLD16(Wm + (size_t)(n0 + chunk * 16 + srow) * K + scol, &Bs[0][chunk * 512]);
    }
    __syncthreads();

    int buf = 0;
    for (int k0 = 0; k0 < K; k0 += 32) {
        if (k0 + 32 < K) {
#pragma unroll
            for (int c = 0; c < ACH; ++c) {
                const int chunk = wid * ACH + c;
                GLD16(A + (size_t)(m0 + chunk * 16 + srow) * K + k0 + 32 + scol,
                      &As[buf ^ 1][chunk * 512]);
            }
#pragma unroll
            for (int c = 0; c < 2; ++c) {
                const int chunk = wid * 2 + c;
                GLD16(Wm + (size_t)(n0 + chunk * 16 + srow) * K + k0 + 32 + scol,
                      &Bs[buf ^ 1][chunk * 512]);
            }
        }
        bf16x8 af[MI], bf[4];
#pragma unroll
        for (int i = 0; i < MI; ++i)
            af[i] = *(const bf16x8*)(&As[buf][(wm + i * 16 + m16) * 32 + ((g ^ sw8) * 8)]);
#pragma unroll
        for (int j = 0; j < 4; ++j)
            bf[j] = *(const bf16x8*)(&Bs[buf][(wn + j * 16 + m16) * 32 + ((g ^ sw8) * 8)]);
#pragma unroll
        for (int i = 0; i < MI; ++i)
#pragma unroll
            for (int j = 0; j < 4; ++j)
                acc[i][j] = __builtin_amdgcn_mfma_f32_16x16x32_bf16(af[i], bf[j], acc[i][j], 0, 0, 0);
        __syncthreads();
        buf ^= 1;
    }

#pragma unroll
    for (int i = 0; i < MI; ++i) {
#pragma unroll
        for (int j = 0; j < 4; ++j) {
            if (MODE == 1) {
#pragma unroll
                for (int r = 0; r < 4; ++r) {
                    const int row = m0 + wm + i * 16 + g * 4 + r;
                    const int col = n0 + wn + j * 16 + m16;
                    ((float*)Cm)[(size_t)row * N + col] = acc[i][j][r];
                }
            } else if (blockIdx.z == 2) {
                // V: 4 consecutive s at fixed dk -> one aligned 8B store
                const int row0 = m0 + wm + i * 16 + g * 4;
                const int col  = n0 + wn + j * 16 + m16;
                const int b = row0 >> 11, s0 = row0 & (S_ - 1);
                const int h = col >> 6,  dk = col & (DK_ - 1);
                union { unsigned short u[4]; uint2 d; } p4;
#pragma unroll
                for (int r = 0; r < 4; ++r) p4.u[r] = f2bf(acc[i][j][r]);
                *(uint2*)((unsigned short*)Cm
                          + ((size_t)((b * H_ + h) * DK_ + dk)) * S_ + s0) = p4.d;
            } else {
#pragma unroll
                for (int r = 0; r < 4; ++r) {
                    const int row = m0 + wm + i * 16 + g * 4 + r;
                    const int col = n0 + wn + j * 16 + m16;
                    const int b = row >> 11, s = row & (S_ - 1);
                    const int h = col >> 6,  dk = col & (DK_ - 1);
                    ((unsigned short*)Cm)[((size_t)((b * H_ + h) * S_ + s)) * DK_ + dk]
                        = f2bf(acc[i][j][r]);
                }
            }
        }
    }
}

// ---------------- RoPE in place on [bh][s][dk] bf16 buffers ----------------
// Q additionally scaled by 0.125*log2(e) so fattn's softmax is a bare exp2.
__global__ __launch_bounds__(256) void k_rope_inplace(
    unsigned short* __restrict__ qh, unsigned short* __restrict__ kh,
    const int* __restrict__ tok)
{
    const int idx = blockIdx.x * 256 + threadIdx.x;
    const int c = idx & 7;
    const int s = (idx >> 3) & (S_ - 1);
    const int b = idx >> 18;
    const size_t off = (size_t)idx * 8;
    const float SC = 0.18033688011112042f;   // 0.125 * log2(e), folded into Q

    const float pos = (float)tok[b * S_ + s];
    float cs[4], sn[4];
#pragma unroll
    for (int i = 0; i < 4; ++i) {
        const int p = c * 4 + i;
        const float inv = exp2f((float)(-2 * p) * (13.287712379549449f / 64.f));
        sincosf(pos * inv, &sn[i], &cs[i]);
    }
    bf16x8 qv = *(bf16x8*)(qh + off);
    bf16x8 kv = *(bf16x8*)(kh + off);
    bf16x8 qo, ko;
#pragma unroll
    for (int i = 0; i < 4; ++i) {
        union { uint32_t u; float f; } q1{(uint32_t)(unsigned short)qv[2*i] << 16};
        union { uint32_t u; float f; } q2{(uint32_t)(unsigned short)qv[2*i+1] << 16};
        qo[2 * i]     = (short)f2bf((q1.f * cs[i] - q2.f * sn[i]) * SC);
        qo[2 * i + 1] = (short)f2bf((q1.f * sn[i] + q2.f * cs[i]) * SC);
        union { uint32_t u; float f; } k1{(uint32_t)(unsigned short)kv[2*i] << 16};
        union { uint32_t u; float f; } k2{(uint32_t)(unsigned short)kv[2*i+1] << 16};
        ko[2 * i]     = (short)f2bf(k1.f * cs[i] - k2.f * sn[i]);
        ko[2 * i + 1] = (short)f2bf(k1.f * sn[i] + k2.f * cs[i]);
    }
    *(bf16x8*)(qh + off) = qo;
    *(bf16x8*)(kh + off) = ko;
}

// ---------------- causal flash attention v10 ----------------
// SHARED-KV FOLD: block (bh, j) processes q-strips A = q-tile j and
// B = q-tile 31-j over ONE kv sweep of nt = 32-j tiles. During the shared
// range t <= j BOTH strips compute from the same staged K/V (frag reads
// amortized 2x); afterwards only B. Staging/barrier/step count drops
// 33 -> 32-j (avg -26%) while total q-strip computes stay 33 (uniform).
// id mapping puts co-resident pair {id, id+256} on the SAME bh with
// j = {aa, 15-aa} -> per-CU step-sum 49 uniform + shared K/V in L2.
// Softmax scale pre-folded into Q (rope); denominator via ones-MFMA.
__global__ __launch_bounds__(256, 2) void k_fattn10(
    const unsigned short* __restrict__ Q,   // [bh][s][64] (pre-scaled)
    const unsigned short* __restrict__ K,   // [bh][s][64]
    const unsigned short* __restrict__ Vt,  // [bh][64][2048]
    unsigned short* __restrict__ O)         // [b][s][1024] bf16
{
    __shared__ __align__(16) unsigned short Ks[2][64 * 64];
    __shared__ __align__(16) unsigned short Vs[2][64 * 64];

    const int tid = threadIdx.x, wid = tid >> 6, lane = tid & 63;
    const int m16 = lane & 15, g = lane >> 4;
    const int id = blockIdx.x;
    const int aa = id & 7;
    const int j  = (id >> 8) ? 15 - aa : aa;            // pair {aa, 15-aa}
    const int bh = (id >> 3) & 31;
    const int b = bh >> 4, h = bh & 15;
    const unsigned short* Qb = Q  + (size_t)bh * S_ * DK_;
    const unsigned short* Kb = K  + (size_t)bh * S_ * DK_;
    const unsigned short* Vb = Vt + (size_t)bh * DK_ * S_;

    const int r8   = lane >> 3;
    const int slot = (lane & 7) ^ r8;
    const int ch0  = wid * 2, ch1 = wid * 2 + 1;

    const f32x4 fz = {0.f, 0.f, 0.f, 0.f};
    union { uint32_t u[4]; bf16x8 v; } one_;
    one_.u[0] = one_.u[1] = one_.u[2] = one_.u[3] = 0x3F803F80u;
    const bf16x8 ones = one_.v;

    // Q fragments for both strips (A = q-tile j, B = q-tile 31-j)
    const int qw0A = j * 64 + wid * 16;
    const int qw0B = (31 - j) * 64 + wid * 16;
    bf16x8 qfA[2], qfB[2];
    {
        const unsigned short* qp = Qb + (size_t)(qw0A + m16) * DK_ + g * 8;
        qfA[0] = *(const bf16x8*)(qp);
        qfA[1] = *(const bf16x8*)(qp + 32);
    }
    {
        const unsigned short* qp = Qb + (size_t)(qw0B + m16) * DK_ + g * 8;
        qfB[0] = *(const bf16x8*)(qp);
        qfB[1] = *(const bf16x8*)(qp + 32);
    }

    f32x4 oA[4], oB[4];
#pragma unroll
    for (int i = 0; i < 4; ++i) { oA[i] = fz; oB[i] = fz; }
    f32x4 psA = fz, psB = fz;

    // prologue: stage kv tile 0 into buf 0
    GLD16(Kb + (size_t)(ch0 * 8 + r8) * DK_ + slot * 8, &Ks[0][ch0 * 512]);
    GLD16(Kb + (size_t)(ch1 * 8 + r8) * DK_ + slot * 8, &Ks[0][ch1 * 512]);
    GLD16(Vb + (size_t)(ch0 * 8 + r8) * S_  + slot * 8, &Vs[0][ch0 * 512]);
    GLD16(Vb + (size_t)(ch1 * 8 + r8) * S_  + slot * 8, &Vs[0][ch1 * 512]);
    __syncthreads();

    const int nt = 32 - j;               // kv tiles (covers BOTH strips)
    int buf = 0;
    for (int t = 0; t < nt; ++t) {
        const int kv0 = t * 64;
        if (t + 1 < nt) {
            const int nkv0 = kv0 + 64;
            GLD16(Kb + (size_t)(nkv0 + ch0 * 8 + r8) * DK_ + slot * 8, &Ks[buf ^ 1][ch0 * 512]);
            GLD16(Kb + (size_t)(nkv0 + ch1 * 8 + r8) * DK_ + slot * 8, &Ks[buf ^ 1][ch1 * 512]);
            GLD16(Vb + (size_t)(ch0 * 8 + r8) * S_ + nkv0 + slot * 8, &Vs[buf ^ 1][ch0 * 512]);
            GLD16(Vb + (size_t)(ch1 * 8 + r8) * S_ + nkv0 + slot * 8, &Vs[buf ^ 1][ch1 * 512]);
        }

        const bool actA = (t <= j);      // wave-uniform

        // S^T = K Q^T for B (always) and A (shared range) — shared K frags
        f32x4 scB[4], scA[4];
        __builtin_amdgcn_s_setprio(1);
#pragma unroll
        for (int c = 0; c < 4; ++c) {
            const int row = c * 16 + m16, rr = row & 7;
            bf16x8 kf0 = *(const bf16x8*)(&Ks[buf][row * 64 + ((g ^ rr) << 3)]);
            bf16x8 kf1 = *(const bf16x8*)(&Ks[buf][row * 64 + (((4 + g) ^ rr) << 3)]);
            f32x4 z = fz;
            z = __builtin_amdgcn_mfma_f32_16x16x32_bf16(kf0, qfB[0], z, 0, 0, 0);
            z = __builtin_amdgcn_mfma_f32_16x16x32_bf16(kf1, qfB[1], z, 0, 0, 0);
            scB[c] = z;
            if (actA) {
                f32x4 za = fz;
                za = __builtin_amdgcn_mfma_f32_16x16x32_bf16(kf0, qfA[0], za, 0, 0, 0);
                za = __builtin_amdgcn_mfma_f32_16x16x32_bf16(kf1, qfA[1], za, 0, 0, 0);
                scA[c] = za;
            }
        }
        __builtin_amdgcn_s_setprio(0);

        // V B-frags (shared by both strips), hoisted above softmax
        bf16x8 vf[2][4];
#pragma unroll
        for (int c2 = 0; c2 < 4; ++c2) {
            const int rv = (c2 * 16 + m16) & 7;
            vf[0][c2] = *(const bf16x8*)(&Vs[buf][(c2 * 16 + m16) * 64 + ((g ^ rv) << 3)]);
            vf[1][c2] = *(const bf16x8*)(&Vs[buf][(c2 * 16 + m16) * 64 + (((4 + g) ^ rv) << 3)]);
        }

        // ---- strip B: softmax + PV ----
        {
            const bool maskT = (t == nt - 1);
            const int qrow = qw0B + m16;
            uint32_t pk[4][2];
#pragma unroll
            for (int c = 0; c < 4; ++c) {
                float p[4];
#pragma unroll
                for (int r = 0; r < 4; ++r) {
                    float v = exp2f(scB[c][r]);
                    if (maskT && (kv0 + c * 16 + g * 4 + r > qrow)) v = 0.f;
                    p[r] = v;
                }
                pk[c][0] = cvtpk(p[0], p[1]);
                pk[c][1] = cvtpk(p[2], p[3]);
            }
            bf16x8 pf[2];
#pragma unroll
            for (int ks = 0; ks < 2; ++ks) {
                uint32_t ylo = pk[2 * ks][0], zlo = pk[2 * ks + 1][0];
                ps32(ylo, zlo); ps16(ylo, zlo);
                uint32_t yhi = pk[2 * ks][1], zhi = pk[2 * ks + 1][1];
                ps32(yhi, zhi); ps16(yhi, zhi);
                union { uint32_t u[4]; bf16x8 v; } fu;
                fu.u[0] = ylo; fu.u[1] = yhi; fu.u[2] = zlo; fu.u[3] = zhi;
                pf[ks] = fu.v;
            }
            __builtin_amdgcn_s_setprio(1);
#pragma unroll
            for (int c2 = 0; c2 < 4; ++c2) {
                oB[c2] = __builtin_amdgcn_mfma_f32_16x16x32_bf16(pf[0], vf[0][c2], oB[c2], 0, 0, 0);
                oB[c2] = __builtin_amdgcn_mfma_f32_16x16x32_bf16(pf[1], vf[1][c2], oB[c2], 0, 0, 0);
            }
            psB = __builtin_amdgcn_mfma_f32_16x16x32_bf16(pf[0], ones, psB, 0, 0, 0);
            psB = __builtin_amdgcn_mfma_f32_16x16x32_bf16(pf[1], ones, psB, 0, 0, 0);
            __builtin_amdgcn_s_setprio(0);
        }

        // ---- strip A: softmax + PV (shared kv range only) ----
        if (actA) {
            const bool maskT = (t == j);
            const int qrow = qw0A + m16;
            uint32_t pk[4][2];
#pragma unroll
            for (int c = 0; c < 4; ++c) {
                float p[4];
#pragma unroll
                for (int r = 0; r < 4; ++r) {
                    float v = exp2f(scA[c][r]);
                    if (maskT && (kv0 + c * 16 + g * 4 + r > qrow)) v = 0.f;
                    p[r] = v;
                }
                pk[c][0] = cvtpk(p[0], p[1]);
                pk[c][1] = cvtpk(p[2], p[3]);
            }
            bf16x8 pf[2];
#pragma unroll
            for (int ks = 0; ks < 2; ++ks) {
                uint32_t ylo = pk[2 * ks][0], zlo = pk[2 * ks + 1][0];
                ps32(ylo, zlo); ps16(ylo, zlo);
                uint32_t yhi = pk[2 * ks][1], zhi = pk[2 * ks + 1][1];
                ps32(yhi, zhi); ps16(yhi, zhi);
                union { uint32_t u[4]; bf16x8 v; } fu;
                fu.u[0] = ylo; fu.u[1] = yhi; fu.u[2] = zlo; fu.u[3] = zhi;
                pf[ks] = fu.v;
            }
            __builtin_amdgcn_s_setprio(1);
#pragma unroll
            for (int c2 = 0; c2 < 4; ++c2) {
                oA[c2] = __builtin_amdgcn_mfma_f32_16x16x32_bf16(pf[0], vf[0][c2], oA[c2], 0, 0, 0);
                oA[c2] = __builtin_amdgcn_mfma_f32_16x16x32_bf16(pf[1], vf[1][c2], oA[c2], 0, 0, 0);
            }
            psA = __builtin_amdgcn_mfma_f32_16x16x32_bf16(pf[0], ones, psA, 0, 0, 0);
            psA = __builtin_amdgcn_mfma_f32_16x16x32_bf16(pf[1], ones, psA, 0, 0, 0);
            __builtin_amdgcn_s_setprio(0);
        }

        __syncthreads();
        buf ^= 1;
    }

    // epilogue: denominators per-reg in o's layout — no shuffles
    {
        float lrq[4];
#pragma unroll
        for (int r = 0; r < 4; ++r) lrq[r] = 1.f / psA[r];
#pragma unroll
        for (int c2 = 0; c2 < 4; ++c2)
#pragma unroll
            for (int r = 0; r < 4; ++r) {
                const int orow = qw0A + g * 4 + r;
                const int ocol = h * DK_ + c2 * 16 + m16;
                O[((size_t)(b * S_ + orow)) * D_ + ocol] = f2bf(oA[c2][r] * lrq[r]);
            }
    }
    {
        float lrq[4];
#pragma unroll
        for (int r = 0; r < 4; ++r) lrq[r] = 1.f / psB[r];
#pragma unroll
        for (int c2 = 0; c2 < 4; ++c2)
#pragma unroll
            for (int r = 0; r < 4; ++r) {
                const int orow = qw0B + g * 4 + r;
                const int ocol = h * DK_ + c2 * 16 + m16;
                O[((size_t)(b * S_ + orow)) * D_ + ocol] = f2bf(oB[c2][r] * lrq[r]);
            }
    }
}

// ---------------- host launcher ----------------
extern "C" void kernel_launch(void* const* d_in, const int* in_sizes, int n_in,
                              void* d_out, int out_size, void* d_ws, size_t ws_size,
                              hipStream_t stream) {
    (void)in_sizes; (void)n_in; (void)out_size; (void)ws_size;
    const float* x   = (const float*)d_in[0];
    const float* Wq  = (const float*)d_in[1];
    const float* Wk  = (const float*)d_in[2];
    const float* Wv  = (const float*)d_in[3];
    const float* Wo  = (const float*)d_in[4];
    const int*   tok = (const int*)d_in[5];

    char* ws = (char*)d_ws;
    const size_t MB = 1u << 20;
    unsigned short* xb  = (unsigned short*)(ws + 0 * MB);   // 8 MB  [4096][1024] bf16
    unsigned short* wqb = (unsigned short*)(ws + 8 * MB);   // 2 MB each
    unsigned short* wkb = (unsigned short*)(ws + 10 * MB);
    unsigned short* wvb = (unsigned short*)(ws + 12 * MB);
    unsigned short* wob = (unsigned short*)(ws + 14 * MB);
    unsigned short* qh  = (unsigned short*)(ws + 16 * MB);  // 8 MB  [bh][s][64]
    unsigned short* kh  = (unsigned short*)(ws + 24 * MB);
    unsigned short* vh  = (unsigned short*)(ws + 32 * MB);  // [bh][64][2048] (V^T)
    unsigned short* ao  = (unsigned short*)(ws + 40 * MB);  // 8 MB  [b][s][1024]

    // 1) unified prep: x->bf16, weights->bf16 (one launch)
    k_prep<<<8192, 256, 0, stream>>>(x, Wq, Wk, Wv, Wo,
                                     xb, wqb, wkb, wvb, wob);

    // 2) fused QKV projection -> head layout bf16 (V transposed, packed store)
    k_gemm_bt<0, 128><<<dim3(32, 8, 3), 256, 0, stream>>>(
        xb, wqb, wkb, wvb, qh, kh, vh, B_ * S_, D_, D_);

    // 3) RoPE in place on Q,K (softmax scale folded into Q)
    k_rope_inplace<<<2048, 256, 0, stream>>>(qh, kh, tok);

    // 4) causal flash attention -> [b][s][e] bf16
    k_fattn10<<<dim3(512), 256, 0, stream>>>(qh, kh, vh, ao);

    // 5) output projection -> f32 d_out (TM=64: 512 blocks, 2/CU)
    k_gemm_bt<1, 64><<<dim3(64, 8, 1), 256, 0, stream>>>(
        ao, wob, wob, wob, d_out, d_out, d_out, B_ * S_, D_, D_);
}

// Round 16
// 117.206 us; speedup vs baseline: 1.0100x; 1.0100x over previous
//
#include <hip/hip_runtime.h>
#include <stdint.h>

#define B_  2
#define S_  2048
#define D_  1024
#define H_  16
#define DK_ 64

using bf16x8 = __attribute__((ext_vector_type(8))) short;
using f32x4  = __attribute__((ext_vector_type(4))) float;

__device__ __forceinline__ unsigned short f2bf(float f) {
    union { float f; uint32_t u; } v; v.f = f;
    uint32_t r = v.u + 0x7FFFu + ((v.u >> 16) & 1u);
    return (unsigned short)(r >> 16);
}

// pack two f32 -> one u32 of two bf16 (low = s0), RNE in HW
__device__ __forceinline__ uint32_t cvtpk(float lo, float hi) {
    uint32_t r;
    asm("v_cvt_pk_bf16_f32 %0, %1, %2" : "=v"(r) : "v"(lo), "v"(hi));
    return r;
}
// a' = {a(0-31), b(0-31)} ; b' = {a(32-63), b(32-63)}
__device__ __forceinline__ void ps32(uint32_t& a, uint32_t& b) {
    asm volatile("v_permlane32_swap_b32 %0, %1" : "+v"(a), "+v"(b));
}
// 16-lane rows: odd rows of a <-> even rows of b
__device__ __forceinline__ void ps16(uint32_t& a, uint32_t& b) {
    asm volatile("v_permlane16_swap_b32 %0, %1" : "+v"(a), "+v"(b));
}

// async global->LDS, 16B per lane; LDS dest is wave-uniform base + lane*16
#define GLD16(G, L) __builtin_amdgcn_global_load_lds( \
    (const __attribute__((address_space(1))) void*)(const void*)(G), \
    (__attribute__((address_space(3))) void*)(void*)(L), 16, 0, 0)

// ---------------- unified prep: x->bf16 and 4 weights->bf16 ----------------
// grid 8192: [0,4096) x-convert, [4096,8192) weights
__global__ __launch_bounds__(256) void k_prep(
    const float* __restrict__ x,
    const float* __restrict__ Wq, const float* __restrict__ Wk,
    const float* __restrict__ Wv, const float* __restrict__ Wo,
    unsigned short* __restrict__ xb,
    unsigned short* __restrict__ wqb, unsigned short* __restrict__ wkb,
    unsigned short* __restrict__ wvb, unsigned short* __restrict__ wob)
{
    const int bid = blockIdx.x, tid = threadIdx.x;
    const float* s;
    unsigned short* d;
    int i;
    if (bid < 4096) {
        s = x; d = xb; i = bid * 256 + tid;
    } else {
        const int w = (bid - 4096) >> 10;
        s = w == 0 ? Wq : w == 1 ? Wk : w == 2 ? Wv : Wo;
        d = w == 0 ? wqb : w == 1 ? wkb : w == 2 ? wvb : wob;
        i = ((bid - 4096) & 1023) * 256 + tid;
    }
    float4 v = ((const float4*)s)[i];
    union { unsigned short u[4]; uint2 dd; } o;
    o.u[0] = f2bf(v.x); o.u[1] = f2bf(v.y); o.u[2] = f2bf(v.z); o.u[3] = f2bf(v.w);
    ((uint2*)d)[i] = o.dd;
}

// ---------------- GEMM: C[m][n] = sum_k A[m][k] * W[n][k]  (B^T input) ------
// conflict-free XOR swizzle (both-sides) + 2-phase prefetch (round-8 proven).
// TM = tile M (128 or 64). TM=64 doubles blocks for the output projection.
template<int MODE, int TM>
__global__ __launch_bounds__(256) void k_gemm_bt(
    const unsigned short* __restrict__ A,
    const unsigned short* __restrict__ W0,
    const unsigned short* __restrict__ W1,
    const unsigned short* __restrict__ W2,
    void* __restrict__ C0, void* __restrict__ C1, void* __restrict__ C2,
    int M, int N, int K)
{
    constexpr int MI  = TM / 32;       // m-frags per wave (128->4, 64->2)
    constexpr int ACH = TM / 64;       // A chunks staged per wave
    __shared__ __align__(16) unsigned short As[2][TM * 32];
    __shared__ __align__(16) unsigned short Bs[2][128 * 32];

    const int tid  = threadIdx.x;
    const int wid  = tid >> 6, lane = tid & 63;
    const int m16  = lane & 15, g = lane >> 4;
    const int m0   = blockIdx.x * TM, n0 = blockIdx.y * 128;
    const unsigned short* Wm = blockIdx.z == 0 ? W0 : (blockIdx.z == 1 ? W1 : W2);
    void* Cm = blockIdx.z == 0 ? C0 : (blockIdx.z == 1 ? C1 : C2);

    const int wm = (wid >> 1) * (TM / 2), wn = (wid & 1) * 64;
    const int srow = lane >> 2;
    const int scol = ((lane & 3) ^ ((lane >> 3) & 3)) * 8;
    const int sw8  = (m16 >> 1) & 3;

    const f32x4 fz = {0.f, 0.f, 0.f, 0.f};
    f32x4 acc[MI][4];
#pragma unroll
    for (int i = 0; i < MI; ++i)
#pragma unroll
        for (int j = 0; j < 4; ++j) acc[i][j] = fz;

#pragma unroll
    for (int c = 0; c < ACH; ++c) {
        const int chunk = wid * ACH + c;
        GLD16(A + (size_t)(m0 + chunk * 16 + srow) * K + scol, &As[0][chunk * 512]);
    }
#pragma unroll
    for (int c = 0; c < 2; ++c) {
        const int chunk = wid * 2 + c;
        GLD16(Wm + (size_t)(n0 + chunk * 16 + srow) * K + scol, &Bs[0][chunk * 512]);
    }
    __syncthreads();

    int buf = 0;
    for (int k0 = 0; k0 < K; k0 += 32) {
        if (k0 + 32 < K) {
#pragma unroll
            for (int c = 0; c < ACH; ++c) {
                const int chunk = wid * ACH + c;
                GLD16(A + (size_t)(m0 + chunk * 16 + srow) * K + k0 + 32 + scol,
                      &As[buf ^ 1][chunk * 512]);
            }
#pragma unroll
            for (int c = 0; c < 2; ++c) {
                const int chunk = wid * 2 + c;
                GLD16(Wm + (size_t)(n0 + chunk * 16 + srow) * K + k0 + 32 + scol,
                      &Bs[buf ^ 1][chunk * 512]);
            }
        }
        bf16x8 af[MI], bf[4];
#pragma unroll
        for (int i = 0; i < MI; ++i)
            af[i] = *(const bf16x8*)(&As[buf][(wm + i * 16 + m16) * 32 + ((g ^ sw8) * 8)]);
#pragma unroll
        for (int j = 0; j < 4; ++j)
            bf[j] = *(const bf16x8*)(&Bs[buf][(wn + j * 16 + m16) * 32 + ((g ^ sw8) * 8)]);
#pragma unroll
        for (int i = 0; i < MI; ++i)
#pragma unroll
            for (int j = 0; j < 4; ++j)
                acc[i][j] = __builtin_amdgcn_mfma_f32_16x16x32_bf16(af[i], bf[j], acc[i][j], 0, 0, 0);
        __syncthreads();
        buf ^= 1;
    }

#pragma unroll
    for (int i = 0; i < MI; ++i) {
#pragma unroll
        for (int j = 0; j < 4; ++j) {
            if (MODE == 1) {
#pragma unroll
                for (int r = 0; r < 4; ++r) {
                    const int row = m0 + wm + i * 16 + g * 4 + r;
                    const int col = n0 + wn + j * 16 + m16;
                    ((float*)Cm)[(size_t)row * N + col] = acc[i][j][r];
                }
            } else if (blockIdx.z == 2) {
                // V: 4 consecutive s at fixed dk -> one aligned 8B store
                const int row0 = m0 + wm + i * 16 + g * 4;
                const int col  = n0 + wn + j * 16 + m16;
                const int b = row0 >> 11, s0 = row0 & (S_ - 1);
                const int h = col >> 6,  dk = col & (DK_ - 1);
                union { unsigned short u[4]; uint2 d; } p4;
#pragma unroll
                for (int r = 0; r < 4; ++r) p4.u[r] = f2bf(acc[i][j][r]);
                *(uint2*)((unsigned short*)Cm
                          + ((size_t)((b * H_ + h) * DK_ + dk)) * S_ + s0) = p4.d;
            } else {
#pragma unroll
                for (int r = 0; r < 4; ++r) {
                    const int row = m0 + wm + i * 16 + g * 4 + r;
                    const int col = n0 + wn + j * 16 + m16;
                    const int b = row >> 11, s = row & (S_ - 1);
                    const int h = col >> 6,  dk = col & (DK_ - 1);
                    ((unsigned short*)Cm)[((size_t)((b * H_ + h) * S_ + s)) * DK_ + dk]
                        = f2bf(acc[i][j][r]);
                }
            }
        }
    }
}

// ---------------- RoPE in place on [bh][s][dk] bf16 buffers ----------------
// Q additionally scaled by 0.125*log2(e) so fattn's softmax is a bare exp2.
__global__ __launch_bounds__(256) void k_rope_inplace(
    unsigned short* __restrict__ qh, unsigned short* __restrict__ kh,
    const int* __restrict__ tok)
{
    const int idx = blockIdx.x * 256 + threadIdx.x;
    const int c = idx & 7;
    const int s = (idx >> 3) & (S_ - 1);
    const int b = idx >> 18;
    const size_t off = (size_t)idx * 8;
    const float SC = 0.18033688011112042f;   // 0.125 * log2(e), folded into Q

    const float pos = (float)tok[b * S_ + s];
    float cs[4], sn[4];
#pragma unroll
    for (int i = 0; i < 4; ++i) {
        const int p = c * 4 + i;
        const float inv = exp2f((float)(-2 * p) * (13.287712379549449f / 64.f));
        sincosf(pos * inv, &sn[i], &cs[i]);
    }
    bf16x8 qv = *(bf16x8*)(qh + off);
    bf16x8 kv = *(bf16x8*)(kh + off);
    bf16x8 qo, ko;
#pragma unroll
    for (int i = 0; i < 4; ++i) {
        union { uint32_t u; float f; } q1{(uint32_t)(unsigned short)qv[2*i] << 16};
        union { uint32_t u; float f; } q2{(uint32_t)(unsigned short)qv[2*i+1] << 16};
        qo[2 * i]     = (short)f2bf((q1.f * cs[i] - q2.f * sn[i]) * SC);
        qo[2 * i + 1] = (short)f2bf((q1.f * sn[i] + q2.f * cs[i]) * SC);
        union { uint32_t u; float f; } k1{(uint32_t)(unsigned short)kv[2*i] << 16};
        union { uint32_t u; float f; } k2{(uint32_t)(unsigned short)kv[2*i+1] << 16};
        ko[2 * i]     = (short)f2bf(k1.f * cs[i] - k2.f * sn[i]);
        ko[2 * i + 1] = (short)f2bf(k1.f * sn[i] + k2.f * cs[i]);
    }
    *(bf16x8*)(qh + off) = qo;
    *(bf16x8*)(kh + off) = ko;
}

// ---------------- causal flash attention v10b ----------------
// SHARED-KV FOLD with XCD-LOCAL id decode. v10's regression was a locality
// bug: aa = id&7 made XCD index == aa, spreading all 32 heads across every
// XCD (16 MB >> 4 MB L2 -> FETCH 70 MB, HBM-bound). Fix: bh's low 3 bits
// = id's low 3 bits (bh%8 == XCD id, 4 heads/XCD = 2 MB, L2-fits), with
// aa in bits [7:5] and group in bit 8 so co-resident pairs {id, id+256}
// still share bh and take j = {aa, 15-aa} (uniform 49 steps/CU).
// Block (bh, j): strips A = q-tile j, B = q-tile 31-j over one kv sweep of
// 32-j tiles; both strips share staged K/V in range t <= j.
__global__ __launch_bounds__(256, 2) void k_fattn10(
    const unsigned short* __restrict__ Q,   // [bh][s][64] (pre-scaled)
    const unsigned short* __restrict__ K,   // [bh][s][64]
    const unsigned short* __restrict__ Vt,  // [bh][64][2048]
    unsigned short* __restrict__ O)         // [b][s][1024] bf16
{
    __shared__ __align__(16) unsigned short Ks[2][64 * 64];
    __shared__ __align__(16) unsigned short Vs[2][64 * 64];

    const int tid = threadIdx.x, wid = tid >> 6, lane = tid & 63;
    const int m16 = lane & 15, g = lane >> 4;
    const int id = blockIdx.x;
    const int bh = (id & 7) | (((id >> 3) & 3) << 3);   // bh%8 == id%8 (XCD-local)
    const int aa = (id >> 5) & 7;
    const int j  = (id >> 8) ? 15 - aa : aa;            // pair {aa, 15-aa}
    const int b = bh >> 4, h = bh & 15;
    const unsigned short* Qb = Q  + (size_t)bh * S_ * DK_;
    const unsigned short* Kb = K  + (size_t)bh * S_ * DK_;
    const unsigned short* Vb = Vt + (size_t)bh * DK_ * S_;

    const int r8   = lane >> 3;
    const int slot = (lane & 7) ^ r8;
    const int ch0  = wid * 2, ch1 = wid * 2 + 1;

    const f32x4 fz = {0.f, 0.f, 0.f, 0.f};
    union { uint32_t u[4]; bf16x8 v; } one_;
    one_.u[0] = one_.u[1] = one_.u[2] = one_.u[3] = 0x3F803F80u;
    const bf16x8 ones = one_.v;

    // Q fragments for both strips (A = q-tile j, B = q-tile 31-j)
    const int qw0A = j * 64 + wid * 16;
    const int qw0B = (31 - j) * 64 + wid * 16;
    bf16x8 qfA[2], qfB[2];
    {
        const unsigned short* qp = Qb + (size_t)(qw0A + m16) * DK_ + g * 8;
        qfA[0] = *(const bf16x8*)(qp);
        qfA[1] = *(const bf16x8*)(qp + 32);
    }
    {
        const unsigned short* qp = Qb + (size_t)(qw0B + m16) * DK_ + g * 8;
        qfB[0] = *(const bf16x8*)(qp);
        qfB[1] = *(const bf16x8*)(qp + 32);
    }

    f32x4 oA[4], oB[4];
#pragma unroll
    for (int i = 0; i < 4; ++i) { oA[i] = fz; oB[i] = fz; }
    f32x4 psA = fz, psB = fz;

    // prologue: stage kv tile 0 into buf 0
    GLD16(Kb + (size_t)(ch0 * 8 + r8) * DK_ + slot * 8, &Ks[0][ch0 * 512]);
    GLD16(Kb + (size_t)(ch1 * 8 + r8) * DK_ + slot * 8, &Ks[0][ch1 * 512]);
    GLD16(Vb + (size_t)(ch0 * 8 + r8) * S_  + slot * 8, &Vs[0][ch0 * 512]);
    GLD16(Vb + (size_t)(ch1 * 8 + r8) * S_  + slot * 8, &Vs[0][ch1 * 512]);
    __syncthreads();

    const int nt = 32 - j;               // kv tiles (covers BOTH strips)
    int buf = 0;
    for (int t = 0; t < nt; ++t) {
        const int kv0 = t * 64;
        if (t + 1 < nt) {
            const int nkv0 = kv0 + 64;
            GLD16(Kb + (size_t)(nkv0 + ch0 * 8 + r8) * DK_ + slot * 8, &Ks[buf ^ 1][ch0 * 512]);
            GLD16(Kb + (size_t)(nkv0 + ch1 * 8 + r8) * DK_ + slot * 8, &Ks[buf ^ 1][ch1 * 512]);
            GLD16(Vb + (size_t)(ch0 * 8 + r8) * S_ + nkv0 + slot * 8, &Vs[buf ^ 1][ch0 * 512]);
            GLD16(Vb + (size_t)(ch1 * 8 + r8) * S_ + nkv0 + slot * 8, &Vs[buf ^ 1][ch1 * 512]);
        }

        const bool actA = (t <= j);      // wave-uniform

        // S^T = K Q^T for B (always) and A (shared range) — shared K frags
        f32x4 scB[4], scA[4];
        __builtin_amdgcn_s_setprio(1);
#pragma unroll
        for (int c = 0; c < 4; ++c) {
            const int row = c * 16 + m16, rr = row & 7;
            bf16x8 kf0 = *(const bf16x8*)(&Ks[buf][row * 64 + ((g ^ rr) << 3)]);
            bf16x8 kf1 = *(const bf16x8*)(&Ks[buf][row * 64 + (((4 + g) ^ rr) << 3)]);
            f32x4 z = fz;
            z = __builtin_amdgcn_mfma_f32_16x16x32_bf16(kf0, qfB[0], z, 0, 0, 0);
            z = __builtin_amdgcn_mfma_f32_16x16x32_bf16(kf1, qfB[1], z, 0, 0, 0);
            scB[c] = z;
            if (actA) {
                f32x4 za = fz;
                za = __builtin_amdgcn_mfma_f32_16x16x32_bf16(kf0, qfA[0], za, 0, 0, 0);
                za = __builtin_amdgcn_mfma_f32_16x16x32_bf16(kf1, qfA[1], za, 0, 0, 0);
                scA[c] = za;
            }
        }
        __builtin_amdgcn_s_setprio(0);

        // V B-frags (shared by both strips), hoisted above softmax
        bf16x8 vf[2][4];
#pragma unroll
        for (int c2 = 0; c2 < 4; ++c2) {
            const int rv = (c2 * 16 + m16) & 7;
            vf[0][c2] = *(const bf16x8*)(&Vs[buf][(c2 * 16 + m16) * 64 + ((g ^ rv) << 3)]);
            vf[1][c2] = *(const bf16x8*)(&Vs[buf][(c2 * 16 + m16) * 64 + (((4 + g) ^ rv) << 3)]);
        }

        // ---- strip B: softmax + PV ----
        {
            const bool maskT = (t == nt - 1);
            const int qrow = qw0B + m16;
            uint32_t pk[4][2];
#pragma unroll
            for (int c = 0; c < 4; ++c) {
                float p[4];
#pragma unroll
                for (int r = 0; r < 4; ++r) {
                    float v = exp2f(scB[c][r]);
                    if (maskT && (kv0 + c * 16 + g * 4 + r > qrow)) v = 0.f;
                    p[r] = v;
                }
                pk[c][0] = cvtpk(p[0], p[1]);
                pk[c][1] = cvtpk(p[2], p[3]);
            }
            bf16x8 pf[2];
#pragma unroll
            for (int ks = 0; ks < 2; ++ks) {
                uint32_t ylo = pk[2 * ks][0], zlo = pk[2 * ks + 1][0];
                ps32(ylo, zlo); ps16(ylo, zlo);
                uint32_t yhi = pk[2 * ks][1], zhi = pk[2 * ks + 1][1];
                ps32(yhi, zhi); ps16(yhi, zhi);
                union { uint32_t u[4]; bf16x8 v; } fu;
                fu.u[0] = ylo; fu.u[1] = yhi; fu.u[2] = zlo; fu.u[3] = zhi;
                pf[ks] = fu.v;
            }
            __builtin_amdgcn_s_setprio(1);
#pragma unroll
            for (int c2 = 0; c2 < 4; ++c2) {
                oB[c2] = __builtin_amdgcn_mfma_f32_16x16x32_bf16(pf[0], vf[0][c2], oB[c2], 0, 0, 0);
                oB[c2] = __builtin_amdgcn_mfma_f32_16x16x32_bf16(pf[1], vf[1][c2], oB[c2], 0, 0, 0);
            }
            psB = __builtin_amdgcn_mfma_f32_16x16x32_bf16(pf[0], ones, psB, 0, 0, 0);
            psB = __builtin_amdgcn_mfma_f32_16x16x32_bf16(pf[1], ones, psB, 0, 0, 0);
            __builtin_amdgcn_s_setprio(0);
        }

        // ---- strip A: softmax + PV (shared kv range only) ----
        if (actA) {
            const bool maskT = (t == j);
            const int qrow = qw0A + m16;
            uint32_t pk[4][2];
#pragma unroll
            for (int c = 0; c < 4; ++c) {
                float p[4];
#pragma unroll
                for (int r = 0; r < 4; ++r) {
                    float v = exp2f(scA[c][r]);
                    if (maskT && (kv0 + c * 16 + g * 4 + r > qrow)) v = 0.f;
                    p[r] = v;
                }
                pk[c][0] = cvtpk(p[0], p[1]);
                pk[c][1] = cvtpk(p[2], p[3]);
            }
            bf16x8 pf[2];
#pragma unroll
            for (int ks = 0; ks < 2; ++ks) {
                uint32_t ylo = pk[2 * ks][0], zlo = pk[2 * ks + 1][0];
                ps32(ylo, zlo); ps16(ylo, zlo);
                uint32_t yhi = pk[2 * ks][1], zhi = pk[2 * ks + 1][1];
                ps32(yhi, zhi); ps16(yhi, zhi);
                union { uint32_t u[4]; bf16x8 v; } fu;
                fu.u[0] = ylo; fu.u[1] = yhi; fu.u[2] = zlo; fu.u[3] = zhi;
                pf[ks] = fu.v;
            }
            __builtin_amdgcn_s_setprio(1);
#pragma unroll
            for (int c2 = 0; c2 < 4; ++c2) {
                oA[c2] = __builtin_amdgcn_mfma_f32_16x16x32_bf16(pf[0], vf[0][c2], oA[c2], 0, 0, 0);
                oA[c2] = __builtin_amdgcn_mfma_f32_16x16x32_bf16(pf[1], vf[1][c2], oA[c2], 0, 0, 0);
            }
            psA = __builtin_amdgcn_mfma_f32_16x16x32_bf16(pf[0], ones, psA, 0, 0, 0);
            psA = __builtin_amdgcn_mfma_f32_16x16x32_bf16(pf[1], ones, psA, 0, 0, 0);
            __builtin_amdgcn_s_setprio(0);
        }

        __syncthreads();
        buf ^= 1;
    }

    // epilogue: denominators per-reg in o's layout — no shuffles
    {
        float lrq[4];
#pragma unroll
        for (int r = 0; r < 4; ++r) lrq[r] = 1.f / psA[r];
#pragma unroll
        for (int c2 = 0; c2 < 4; ++c2)
#pragma unroll
            for (int r = 0; r < 4; ++r) {
                const int orow = qw0A + g * 4 + r;
                const int ocol = h * DK_ + c2 * 16 + m16;
                O[((size_t)(b * S_ + orow)) * D_ + ocol] = f2bf(oA[c2][r] * lrq[r]);
            }
    }
    {
        float lrq[4];
#pragma unroll
        for (int r = 0; r < 4; ++r) lrq[r] = 1.f / psB[r];
#pragma unroll
        for (int c2 = 0; c2 < 4; ++c2)
#pragma unroll
            for (int r = 0; r < 4; ++r) {
                const int orow = qw0B + g * 4 + r;
                const int ocol = h * DK_ + c2 * 16 + m16;
                O[((size_t)(b * S_ + orow)) * D_ + ocol] = f2bf(oB[c2][r] * lrq[r]);
            }
    }
}

// ---------------- host launcher ----------------
extern "C" void kernel_launch(void* const* d_in, const int* in_sizes, int n_in,
                              void* d_out, int out_size, void* d_ws, size_t ws_size,
                              hipStream_t stream) {
    (void)in_sizes; (void)n_in; (void)out_size; (void)ws_size;
    const float* x   = (const float*)d_in[0];
    const float* Wq  = (const float*)d_in[1];
    const float* Wk  = (const float*)d_in[2];
    const float* Wv  = (const float*)d_in[3];
    const float* Wo  = (const float*)d_in[4];
    const int*   tok = (const int*)d_in[5];

    char* ws = (char*)d_ws;
    const size_t MB = 1u << 20;
    unsigned short* xb  = (unsigned short*)(ws + 0 * MB);   // 8 MB  [4096][1024] bf16
    unsigned short* wqb = (unsigned short*)(ws + 8 * MB);   // 2 MB each
    unsigned short* wkb = (unsigned short*)(ws + 10 * MB);
    unsigned short* wvb = (unsigned short*)(ws + 12 * MB);
    unsigned short* wob = (unsigned short*)(ws + 14 * MB);
    unsigned short* qh  = (unsigned short*)(ws + 16 * MB);  // 8 MB  [bh][s][64]
    unsigned short* kh  = (unsigned short*)(ws + 24 * MB);
    unsigned short* vh  = (unsigned short*)(ws + 32 * MB);  // [bh][64][2048] (V^T)
    unsigned short* ao  = (unsigned short*)(ws + 40 * MB);  // 8 MB  [b][s][1024]

    // 1) unified prep: x->bf16, weights->bf16 (one launch)
    k_prep<<<8192, 256, 0, stream>>>(x, Wq, Wk, Wv, Wo,
                                     xb, wqb, wkb, wvb, wob);

    // 2) fused QKV projection -> head layout bf16 (V transposed, packed store)
    k_gemm_bt<0, 128><<<dim3(32, 8, 3), 256, 0, stream>>>(
        xb, wqb, wkb, wvb, qh, kh, vh, B_ * S_, D_, D_);

    // 3) RoPE in place on Q,K (softmax scale folded into Q)
    k_rope_inplace<<<2048, 256, 0, stream>>>(qh, kh, tok);

    // 4) causal flash attention -> [b][s][e] bf16
    k_fattn10<<<dim3(512), 256, 0, stream>>>(qh, kh, vh, ao);

    // 5) output projection -> f32 d_out (TM=64: 512 blocks, 2/CU)
    k_gemm_bt<1, 64><<<dim3(64, 8, 1), 256, 0, stream>>>(
        ao, wob, wob, wob, d_out, d_out, d_out, B_ * S_, D_, D_);
}